// Round 3
// baseline (221.103 us; speedup 1.0000x reference)
//
#include <hip/hip_runtime.h>
#include <math.h>

#define IN_DIM 384
#define HID 16
#define NCLS 2
#define BN_EPS 1e-5f
#define MAXG 64

// ---------------- CSR build ----------------
__global__ void k_hist(const int* __restrict__ ei, int E, int* __restrict__ deg) {
    int stride = gridDim.x * blockDim.x;
    for (int e = blockIdx.x * blockDim.x + threadIdx.x; e < E; e += stride)
        atomicAdd(&deg[ei[e]], 1);
}

// Wave-scan allocation of CSR regions (region order across nodes irrelevant).
__global__ void k_alloc(const int* __restrict__ deg, int N, int2* __restrict__ degoffs,
                        int* __restrict__ wcur, int* __restrict__ cursor) {
    int i = blockIdx.x * blockDim.x + threadIdx.x;
    int lane = threadIdx.x & 63;
    int d = (i < N) ? deg[i] : 0;
    int run = d;
#pragma unroll
    for (int s = 1; s < 64; s <<= 1) {
        int v = __shfl_up(run, s, 64);
        if (lane >= s) run += v;
    }
    int total = __shfl(run, 63, 64);
    int base = 0;
    if (lane == 63) base = atomicAdd(cursor, total);
    base = __shfl(base, 63, 64);
    if (i < N) {
        int o = base + run - d;
        degoffs[i] = make_int2(o, d);
        wcur[i] = o;
    }
}

__global__ void k_scatter(const int* __restrict__ ei, const int* __restrict__ ej, int E,
                          int* __restrict__ wcur, int* __restrict__ colidx) {
    int stride = gridDim.x * blockDim.x;
    for (int e = blockIdx.x * blockDim.x + threadIdx.x; e < E; e += stride) {
        int i = ei[e];
        int pos = atomicAdd(&wcur[i], 1);
        colidx[pos] = ej[e];
    }
}

// ---------------- pre-projection y[i][0..15]=x@W_mean.T, y[i][16..31]=x@W_root.T
// Block: 64 nodes, 4 waves (one 8-output group each). x staged through LDS with
// coalesced float4 loads; compute reads are stride-98 (conflict-free b64).
// Weight addresses are wave-uniform -> scalar loads.
__global__ __launch_bounds__(256) void k_proj(const float* __restrict__ x,
                                              const float* __restrict__ wl,
                                              const float* __restrict__ wr, int N,
                                              float* __restrict__ y) {
    __shared__ float shX[64 * 98];
    int t = threadIdx.x;
    int lane = t & 63;
    int wid = __builtin_amdgcn_readfirstlane(t >> 6);
    const float* wb = (wid < 2) ? (wl + (wid * 8) * (2 * IN_DIM))
                                : (wr + ((wid - 2) * 8) * IN_DIM);
    const int wstr = (wid < 2) ? (2 * IN_DIM) : IN_DIM;
    int base = blockIdx.x * 64;
    int r = t >> 2, q = t & 3;
    int gr = min(base + r, N - 1);
    const float* gxr = x + (size_t)gr * IN_DIM;
    float acc[8];
#pragma unroll
    for (int k = 0; k < 8; k++) acc[k] = 0.f;
    for (int kk = 0; kk < 4; kk++) {
        int kc = kk * 96;
        __syncthreads();
#pragma unroll
        for (int it = 0; it < 6; it++) {
            int c4 = q + it * 4;  // float4 column within chunk
            float4 v = *(const float4*)(gxr + kc + c4 * 4);
            float* dst = shX + r * 98 + c4 * 4;
            *(float2*)dst = make_float2(v.x, v.y);
            *(float2*)(dst + 2) = make_float2(v.z, v.w);
        }
        __syncthreads();
        const float2* xrow = (const float2*)(shX + lane * 98);
        const float* wc = wb + kc;
#pragma unroll 12
        for (int c = 0; c < 48; c++) {
            float2 xv = xrow[c];
#pragma unroll
            for (int r8 = 0; r8 < 8; r8++) {
                acc[r8] = fmaf(xv.x, wc[r8 * wstr + 2 * c], acc[r8]);
                acc[r8] = fmaf(xv.y, wc[r8 * wstr + 2 * c + 1], acc[r8]);
            }
        }
    }
    int i = base + lane;
    if (i < N) {
        float* yo = y + (size_t)i * 32 + wid * 8;
        ((float4*)yo)[0] = make_float4(acc[0], acc[1], acc[2], acc[3]);
        ((float4*)yo)[1] = make_float4(acc[4], acc[5], acc[6], acc[7]);
    }
}

// ---------------- wave-per-4-nodes: gather each node's neighbors (384-dim max
// as 3 float2/lane), then ONE pass over W_max in LDS serves all 4 nodes;
// reduce-scatter (not butterfly) finishes the 64 dot-products; contiguous
// 256B h-write; fused BN-stats.
__global__ __launch_bounds__(256) void k_node(const float* __restrict__ x,
                                              const float* __restrict__ y,
                                              const float* __restrict__ wl,
                                              const float* __restrict__ lb,
                                              const int2* __restrict__ degoffs,
                                              const int* __restrict__ colidx, int N,
                                              float* __restrict__ h,
                                              float* __restrict__ stats) {
    __shared__ float shW[16 * IN_DIM];
    __shared__ float shS[32];
    for (int idx = threadIdx.x; idx < 16 * IN_DIM; idx += blockDim.x) {
        int k = idx / IN_DIM, d = idx - k * IN_DIM;
        shW[k * IN_DIM + d] = wl[k * (2 * IN_DIM) + IN_DIM + d];
    }
    if (threadIdx.x < 32) shS[threadIdx.x] = 0.f;
    __syncthreads();
    int lane = threadIdx.x & 63;
    int wid = threadIdx.x >> 6;
    int nwaves = gridDim.x * 4;
    int kq = ((lane >> 4) << 2) + (lane & 3);  // channel this lane finalizes
    int nq = (lane & 15) >> 2;                 // node slot this lane finalizes
    float lbv = lb[kq];
    const float* xl = x + 2 * lane;            // this lane's dim base (dims 2l,2l+1,...)
    const float* wp = shW + 2 * lane;
    float sAcc = 0.f, s2Acc = 0.f;
    int ngroups = (N + 3) >> 2;
    for (int g = blockIdx.x * 4 + wid; g < ngroups; g += nwaves) {
        int ibase = g << 2;
        float2 mx[4][3];
        float s16[4];
        int dgv[4];
#pragma unroll
        for (int n = 0; n < 4; n++) {
            int i = ibase + n;
            float2 m0 = make_float2(-INFINITY, -INFINITY), m1 = m0, m2 = m0;
            float s = 0.f;
            int dg = 0;
            if (i < N) {
                int2 dof = degoffs[i];
                int beg = dof.x;
                dg = dof.y;
                for (int e0 = 0; e0 < dg; e0 += 64) {
                    int nv = min(64, dg - e0);
                    int jv = (lane < nv) ? colidx[beg + e0 + lane] : 0;
                    int eb = 0;
                    for (; eb + 4 <= nv; eb += 4) {
                        int j0 = __shfl(jv, eb, 64), j1 = __shfl(jv, eb + 1, 64);
                        int j2 = __shfl(jv, eb + 2, 64), j3 = __shfl(jv, eb + 3, 64);
                        const float* p0 = xl + (size_t)j0 * IN_DIM;
                        const float* p1 = xl + (size_t)j1 * IN_DIM;
                        const float* p2 = xl + (size_t)j2 * IN_DIM;
                        const float* p3 = xl + (size_t)j3 * IN_DIM;
                        float2 a00 = *(const float2*)p0, a01 = *(const float2*)(p0 + 128),
                               a02 = *(const float2*)(p0 + 256);
                        float2 a10 = *(const float2*)p1, a11 = *(const float2*)(p1 + 128),
                               a12 = *(const float2*)(p1 + 256);
                        float2 a20 = *(const float2*)p2, a21 = *(const float2*)(p2 + 128),
                               a22 = *(const float2*)(p2 + 256);
                        float2 a30 = *(const float2*)p3, a31 = *(const float2*)(p3 + 128),
                               a32 = *(const float2*)(p3 + 256);
                        if (lane < HID) {
                            s += y[(size_t)j0 * 32 + lane] + y[(size_t)j1 * 32 + lane] +
                                 y[(size_t)j2 * 32 + lane] + y[(size_t)j3 * 32 + lane];
                        }
                        m0.x = fmaxf(fmaxf(m0.x, fmaxf(a00.x, a10.x)), fmaxf(a20.x, a30.x));
                        m0.y = fmaxf(fmaxf(m0.y, fmaxf(a00.y, a10.y)), fmaxf(a20.y, a30.y));
                        m1.x = fmaxf(fmaxf(m1.x, fmaxf(a01.x, a11.x)), fmaxf(a21.x, a31.x));
                        m1.y = fmaxf(fmaxf(m1.y, fmaxf(a01.y, a11.y)), fmaxf(a21.y, a31.y));
                        m2.x = fmaxf(fmaxf(m2.x, fmaxf(a02.x, a12.x)), fmaxf(a22.x, a32.x));
                        m2.y = fmaxf(fmaxf(m2.y, fmaxf(a02.y, a12.y)), fmaxf(a22.y, a32.y));
                    }
                    for (; eb < nv; eb++) {
                        int j = __shfl(jv, eb, 64);
                        const float* p = xl + (size_t)j * IN_DIM;
                        float2 a0 = *(const float2*)p, a1 = *(const float2*)(p + 128),
                               a2 = *(const float2*)(p + 256);
                        if (lane < HID) s += y[(size_t)j * 32 + lane];
                        m0.x = fmaxf(m0.x, a0.x); m0.y = fmaxf(m0.y, a0.y);
                        m1.x = fmaxf(m1.x, a1.x); m1.y = fmaxf(m1.y, a1.y);
                        m2.x = fmaxf(m2.x, a2.x); m2.y = fmaxf(m2.y, a2.y);
                    }
                }
            }
            if (dg == 0) {  // wave-uniform; isolated/invalid -> max_agg = 0
                m0 = make_float2(0.f, 0.f); m1 = m0; m2 = m0;
            }
            mx[n][0] = m0; mx[n][1] = m1; mx[n][2] = m2;
            s16[n] = s; dgv[n] = dg;
        }
        // projection: one sweep over W serves 4 nodes; reduce-scatter per k-group
        float outv = 0.f;
#pragma unroll
        for (int kg = 0; kg < 4; kg++) {
            float r[16];
#pragma unroll
            for (int kk = 0; kk < 4; kk++) {
                int k = (kg << 2) + kk;
                float2 w0 = *(const float2*)(wp + k * IN_DIM);
                float2 w1 = *(const float2*)(wp + k * IN_DIM + 128);
                float2 w2 = *(const float2*)(wp + k * IN_DIM + 256);
#pragma unroll
                for (int n = 0; n < 4; n++) {
                    float t = mx[n][0].x * w0.x;
                    t = fmaf(mx[n][0].y, w0.y, t);
                    t = fmaf(mx[n][1].x, w1.x, t);
                    t = fmaf(mx[n][1].y, w1.y, t);
                    t = fmaf(mx[n][2].x, w2.x, t);
                    t = fmaf(mx[n][2].y, w2.y, t);
                    r[(n << 2) + kk] = t;
                }
            }
            // reduce-scatter: after 4 stages lane l holds value idx l&15 summed
            // over its 16-lane group; 2 butterfly stages finish all 64 lanes.
#pragma unroll
            for (int s = 0; s < 4; s++) {
                int step = 1 << s;
                bool hi = (lane & step) != 0;
#pragma unroll
                for (int m = 0; m < (8 >> s); m++) {
                    float a = r[2 * m], b = r[2 * m + 1];
                    float send = hi ? a : b;
                    float keep = hi ? b : a;
                    r[m] = keep + __shfl_xor(send, step, 64);
                }
            }
            float v = r[0];
            v += __shfl_xor(v, 16, 64);
            v += __shfl_xor(v, 32, 64);
            if ((lane >> 4) == kg) outv = v;
        }
        // epilogue: lane l owns (node nq, channel kq); h-write is 64 contiguous floats
        int iw = ibase + nq;
        float t0 = __shfl(s16[0], kq, 64), t1 = __shfl(s16[1], kq, 64);
        float t2 = __shfl(s16[2], kq, 64), t3 = __shfl(s16[3], kq, 64);
        float sv = (nq == 0) ? t0 : (nq == 1) ? t1 : (nq == 2) ? t2 : t3;
        int dgs = (nq == 0) ? dgv[0] : (nq == 1) ? dgv[1] : (nq == 2) ? dgv[2] : dgv[3];
        if (iw < N) {
            float mean = sv / (float)max(dgs, 1);
            float hv = mean + outv + y[(size_t)iw * 32 + 16 + kq] + lbv;
            h[(size_t)iw * HID + kq] = hv;
            sAcc += hv;
            s2Acc = fmaf(hv, hv, s2Acc);
        }
    }
    __syncthreads();
    atomicAdd(&shS[kq], sAcc);
    atomicAdd(&shS[16 + kq], s2Acc);
    __syncthreads();
    if (threadIdx.x < 32) atomicAdd(&stats[threadIdx.x], shS[threadIdx.x]);
}

// ---------------- BN + ReLU + global mean pool (LDS pre-aggregation; batch sorted)
__global__ __launch_bounds__(256) void k_pool(const float* __restrict__ h,
                                              const int* __restrict__ batch,
                                              const float* __restrict__ stats,
                                              const float* __restrict__ gamma,
                                              const float* __restrict__ beta, int N,
                                              float* __restrict__ pooled,
                                              int* __restrict__ gcnt) {
    __shared__ float smP[MAXG * HID];
    __shared__ int smC[MAXG];
    for (int idx = threadIdx.x; idx < MAXG * HID; idx += blockDim.x) smP[idx] = 0.f;
    if (threadIdx.x < MAXG) smC[threadIdx.x] = 0;
    __syncthreads();
    int c = threadIdx.x & 15;
    float invN = 1.f / (float)N;
    float mu = stats[c] * invN;
    float var = stats[16 + c] * invN - mu * mu;
    float sc = gamma[c] * rsqrtf(var + BN_EPS);
    float sh = beta[c] - mu * sc;
    int base = blockIdx.x * 1024;
    int endn = min(base + 1024, N);
    for (int idx = base * HID + threadIdx.x; idx < endn * HID; idx += blockDim.x) {
        int n = idx >> 4;
        float v = fmaxf(fmaf(h[idx], sc, sh), 0.f);
        int g = batch[n] & (MAXG - 1);
        atomicAdd(&smP[g * HID + c], v);
        if (c == 0) atomicAdd(&smC[g], 1);
    }
    __syncthreads();
    for (int idx = threadIdx.x; idx < MAXG * HID; idx += blockDim.x)
        if (smP[idx] != 0.f) atomicAdd(&pooled[idx], smP[idx]);
    if (threadIdx.x < MAXG && smC[threadIdx.x]) atomicAdd(&gcnt[threadIdx.x], smC[threadIdx.x]);
}

// ---------------- pooled mean + FC
__global__ void k_final(const float* __restrict__ pooled, const int* __restrict__ gcnt,
                        const float* __restrict__ fcw, const float* __restrict__ fcb, int G,
                        float* __restrict__ out) {
    int g = threadIdx.x;
    if (g < G) {
        float inv = 1.f / (float)max(gcnt[g], 1);
        float o0 = fcb[0], o1 = fcb[1];
#pragma unroll
        for (int ch = 0; ch < HID; ch++) {
            float pv = pooled[g * HID + ch] * inv;
            o0 = fmaf(pv, fcw[ch], o0);
            o1 = fmaf(pv, fcw[HID + ch], o1);
        }
        out[g * NCLS + 0] = o0;
        out[g * NCLS + 1] = o1;
    }
}

extern "C" void kernel_launch(void* const* d_in, const int* in_sizes, int n_in,
                              void* d_out, int out_size, void* d_ws, size_t ws_size,
                              hipStream_t stream) {
    const float* x = (const float*)d_in[0];
    const int* ei = (const int*)d_in[1];
    const int* batch = (const int*)d_in[2];
    const float* wl = (const float*)d_in[4];
    const float* lb = (const float*)d_in[5];
    const float* wr = (const float*)d_in[6];
    const float* gamma = (const float*)d_in[7];
    const float* beta = (const float*)d_in[8];
    const float* fcw = (const float*)d_in[9];
    const float* fcb = (const float*)d_in[10];

    const int N = in_sizes[0] / IN_DIM;
    const int E = in_sizes[1] / 2;
    const int G = out_size / NCLS;
    const int* ej = ei + E;

    size_t off = 0;
    auto take = [&](size_t b) { size_t r = off; off += (b + 255) & ~(size_t)255; return r; };
    size_t deg_off  = take((size_t)N * 4);
    size_t cur_off  = take(4);
    size_t stat_off = take(32 * 4);
    size_t pool_off = take((size_t)MAXG * HID * 4);
    size_t gcnt_off = take((size_t)MAXG * 4);
    size_t zero_bytes = off;
    size_t dof_off  = take((size_t)N * 8);
    size_t wcur_off = take((size_t)N * 4);
    size_t col_off  = take((size_t)E * 4);
    size_t y_off    = take((size_t)N * 32 * 4);
    size_t h_off    = take((size_t)N * HID * 4);
    (void)ws_size;

    char* ws = (char*)d_ws;
    int* deg = (int*)(ws + deg_off);
    int* cursor = (int*)(ws + cur_off);
    float* stats = (float*)(ws + stat_off);
    float* pooled = (float*)(ws + pool_off);
    int* gcnt = (int*)(ws + gcnt_off);
    int2* degoffs = (int2*)(ws + dof_off);
    int* wcur = (int*)(ws + wcur_off);
    int* colidx = (int*)(ws + col_off);
    float* y = (float*)(ws + y_off);
    float* h = (float*)(ws + h_off);

    hipMemsetAsync(d_ws, 0, zero_bytes, stream);

    int eblocks = (E + 255) / 256;
    k_hist<<<eblocks, 256, 0, stream>>>(ei, E, deg);
    k_alloc<<<(N + 255) / 256, 256, 0, stream>>>(deg, N, degoffs, wcur, cursor);
    k_scatter<<<eblocks, 256, 0, stream>>>(ei, ej, E, wcur, colidx);
    k_proj<<<(N + 63) / 64, 256, 0, stream>>>(x, wl, wr, N, y);
    k_node<<<1536, 256, 0, stream>>>(x, y, wl, lb, degoffs, colidx, N, h, stats);
    k_pool<<<(N + 1023) / 1024, 256, 0, stream>>>(h, batch, stats, gamma, beta, N, pooled, gcnt);
    k_final<<<1, 64, 0, stream>>>(pooled, gcnt, fcw, fcb, G, (float*)d_out);
}

// Round 4
// 204.005 us; speedup vs baseline: 1.0838x; 1.0838x over previous
//
#include <hip/hip_runtime.h>
#include <math.h>

#define IN_DIM 384
#define HID 16
#define NCLS 2
#define BN_EPS 1e-5f
#define MAXG 64

// ---------------- CSR build ----------------
__global__ void k_hist(const int* __restrict__ ei, int E, int* __restrict__ deg) {
    int stride = gridDim.x * blockDim.x;
    for (int e = blockIdx.x * blockDim.x + threadIdx.x; e < E; e += stride)
        atomicAdd(&deg[ei[e]], 1);
}

// Wave-scan allocation of CSR regions (region order across nodes irrelevant).
__global__ void k_alloc(const int* __restrict__ deg, int N, int2* __restrict__ degoffs,
                        int* __restrict__ wcur, int* __restrict__ cursor) {
    int i = blockIdx.x * blockDim.x + threadIdx.x;
    int lane = threadIdx.x & 63;
    int d = (i < N) ? deg[i] : 0;
    int run = d;
#pragma unroll
    for (int s = 1; s < 64; s <<= 1) {
        int v = __shfl_up(run, s, 64);
        if (lane >= s) run += v;
    }
    int total = __shfl(run, 63, 64);
    int base = 0;
    if (lane == 63) base = atomicAdd(cursor, total);
    base = __shfl(base, 63, 64);
    if (i < N) {
        int o = base + run - d;
        degoffs[i] = make_int2(o, d);
        wcur[i] = o;
    }
}

__global__ void k_scatter(const int* __restrict__ ei, const int* __restrict__ ej, int E,
                          int* __restrict__ wcur, int* __restrict__ colidx) {
    int stride = gridDim.x * blockDim.x;
    for (int e = blockIdx.x * blockDim.x + threadIdx.x; e < E; e += stride) {
        int i = ei[e];
        int pos = atomicAdd(&wcur[i], 1);
        colidx[pos] = ej[e];
    }
}

// ---------------- pre-projection y[i][0..15]=x@W_mean.T, y[i][16..31]=x@W_root.T
// Block: 512 threads = 8 waves, 64 nodes. Wave w computes 4 output rows
// (w<4: W_mean rows 4w..4w+3; w>=4: W_root rows). Per-chunk weight window is
// 4x96 floats -> SGPR-windowable (unroll 8 => 64 scalars/window, prefetchable).
__global__ __launch_bounds__(512) void k_proj(const float* __restrict__ x,
                                              const float* __restrict__ wl,
                                              const float* __restrict__ wr, int N,
                                              float* __restrict__ y) {
    __shared__ float shX[64 * 98];
    int t = threadIdx.x;
    int lane = t & 63;
    int wid = __builtin_amdgcn_readfirstlane(t >> 6);  // 0..7
    const float* wb = (wid < 4) ? (wl + (wid * 4) * (2 * IN_DIM))
                                : (wr + ((wid - 4) * 4) * IN_DIM);
    const int wstr = (wid < 4) ? (2 * IN_DIM) : IN_DIM;
    int base = blockIdx.x * 64;
    int r = t >> 3, q = t & 7;  // staging: row 0..63, 8 float4-cols of 24
    int gr = min(base + r, N - 1);
    const float* gxr = x + (size_t)gr * IN_DIM;
    float acc[4] = {0.f, 0.f, 0.f, 0.f};
    for (int kk = 0; kk < 4; kk++) {
        int kc = kk * 96;
        __syncthreads();
#pragma unroll
        for (int it = 0; it < 3; it++) {
            int c4 = q + it * 8;
            float4 v = *(const float4*)(gxr + kc + c4 * 4);
            float* dst = shX + r * 98 + c4 * 4;
            *(float2*)dst = make_float2(v.x, v.y);
            *(float2*)(dst + 2) = make_float2(v.z, v.w);
        }
        __syncthreads();
        const float2* xrow = (const float2*)(shX + lane * 98);
        const float* w0 = wb + 0 * wstr + kc;
        const float* w1 = wb + 1 * wstr + kc;
        const float* w2 = wb + 2 * wstr + kc;
        const float* w3 = wb + 3 * wstr + kc;
#pragma unroll 8
        for (int c = 0; c < 48; c++) {
            float2 xv = xrow[c];
            acc[0] = fmaf(xv.x, w0[2 * c], acc[0]);
            acc[0] = fmaf(xv.y, w0[2 * c + 1], acc[0]);
            acc[1] = fmaf(xv.x, w1[2 * c], acc[1]);
            acc[1] = fmaf(xv.y, w1[2 * c + 1], acc[1]);
            acc[2] = fmaf(xv.x, w2[2 * c], acc[2]);
            acc[2] = fmaf(xv.y, w2[2 * c + 1], acc[2]);
            acc[3] = fmaf(xv.x, w3[2 * c], acc[3]);
            acc[3] = fmaf(xv.y, w3[2 * c + 1], acc[3]);
        }
    }
    int i = base + lane;
    if (i < N) {
        float* yo = y + (size_t)i * 32 + ((wid < 4) ? wid * 4 : 16 + (wid - 4) * 4);
        *(float4*)yo = make_float4(acc[0], acc[1], acc[2], acc[3]);
    }
}

// ---------------- wave-per-4-nodes (EXACTLY one group per wave -> perfect
// balance): gather each node's neighbors (384-dim max as 3 float2/lane), one
// sweep over W_max in LDS serves 4 nodes; reduce-scatter finishes the 64
// dot-products; contiguous 256B h-write; fused BN-stats.
__global__ __launch_bounds__(256) void k_node(const float* __restrict__ x,
                                              const float* __restrict__ y,
                                              const float* __restrict__ wl,
                                              const float* __restrict__ lb,
                                              const int2* __restrict__ degoffs,
                                              const int* __restrict__ colidx, int N,
                                              float* __restrict__ h,
                                              float* __restrict__ stats) {
    __shared__ float shW[16 * IN_DIM];
    __shared__ float shS[32];
    for (int idx = threadIdx.x; idx < 16 * IN_DIM; idx += blockDim.x) {
        int k = idx / IN_DIM, d = idx - k * IN_DIM;
        shW[k * IN_DIM + d] = wl[k * (2 * IN_DIM) + IN_DIM + d];
    }
    if (threadIdx.x < 32) shS[threadIdx.x] = 0.f;
    __syncthreads();
    int lane = threadIdx.x & 63;
    int wid = threadIdx.x >> 6;
    int kq = ((lane >> 4) << 2) + (lane & 3);  // channel this lane finalizes
    int nq = (lane & 15) >> 2;                 // node slot this lane finalizes
    float lbv = lb[kq];
    const float* xl = x + 2 * lane;            // this lane's dim base
    const float* wp = shW + 2 * lane;
    float sAcc = 0.f, s2Acc = 0.f;
    int ngroups = (N + 3) >> 2;
    int g = blockIdx.x * 4 + wid;
    if (g < ngroups) {
        int ibase = g << 2;
        float2 mx[4][3];
        float s16[4];
        int dgv[4];
#pragma unroll
        for (int n = 0; n < 4; n++) {
            int i = ibase + n;
            float2 m0 = make_float2(-INFINITY, -INFINITY), m1 = m0, m2 = m0;
            float s = 0.f;
            int dg = 0;
            if (i < N) {
                int2 dof = degoffs[i];
                int beg = dof.x;
                dg = dof.y;
                for (int e0 = 0; e0 < dg; e0 += 64) {
                    int nv = min(64, dg - e0);
                    int jv = (lane < nv) ? colidx[beg + e0 + lane] : 0;
                    int eb = 0;
                    for (; eb + 4 <= nv; eb += 4) {
                        int j0 = __shfl(jv, eb, 64), j1 = __shfl(jv, eb + 1, 64);
                        int j2 = __shfl(jv, eb + 2, 64), j3 = __shfl(jv, eb + 3, 64);
                        const float* p0 = xl + (size_t)j0 * IN_DIM;
                        const float* p1 = xl + (size_t)j1 * IN_DIM;
                        const float* p2 = xl + (size_t)j2 * IN_DIM;
                        const float* p3 = xl + (size_t)j3 * IN_DIM;
                        float2 a00 = *(const float2*)p0, a01 = *(const float2*)(p0 + 128),
                               a02 = *(const float2*)(p0 + 256);
                        float2 a10 = *(const float2*)p1, a11 = *(const float2*)(p1 + 128),
                               a12 = *(const float2*)(p1 + 256);
                        float2 a20 = *(const float2*)p2, a21 = *(const float2*)(p2 + 128),
                               a22 = *(const float2*)(p2 + 256);
                        float2 a30 = *(const float2*)p3, a31 = *(const float2*)(p3 + 128),
                               a32 = *(const float2*)(p3 + 256);
                        if (lane < HID) {
                            s += y[(size_t)j0 * 32 + lane] + y[(size_t)j1 * 32 + lane] +
                                 y[(size_t)j2 * 32 + lane] + y[(size_t)j3 * 32 + lane];
                        }
                        m0.x = fmaxf(fmaxf(m0.x, fmaxf(a00.x, a10.x)), fmaxf(a20.x, a30.x));
                        m0.y = fmaxf(fmaxf(m0.y, fmaxf(a00.y, a10.y)), fmaxf(a20.y, a30.y));
                        m1.x = fmaxf(fmaxf(m1.x, fmaxf(a01.x, a11.x)), fmaxf(a21.x, a31.x));
                        m1.y = fmaxf(fmaxf(m1.y, fmaxf(a01.y, a11.y)), fmaxf(a21.y, a31.y));
                        m2.x = fmaxf(fmaxf(m2.x, fmaxf(a02.x, a12.x)), fmaxf(a22.x, a32.x));
                        m2.y = fmaxf(fmaxf(m2.y, fmaxf(a02.y, a12.y)), fmaxf(a22.y, a32.y));
                    }
                    for (; eb < nv; eb++) {
                        int j = __shfl(jv, eb, 64);
                        const float* p = xl + (size_t)j * IN_DIM;
                        float2 a0 = *(const float2*)p, a1 = *(const float2*)(p + 128),
                               a2 = *(const float2*)(p + 256);
                        if (lane < HID) s += y[(size_t)j * 32 + lane];
                        m0.x = fmaxf(m0.x, a0.x); m0.y = fmaxf(m0.y, a0.y);
                        m1.x = fmaxf(m1.x, a1.x); m1.y = fmaxf(m1.y, a1.y);
                        m2.x = fmaxf(m2.x, a2.x); m2.y = fmaxf(m2.y, a2.y);
                    }
                }
            }
            if (dg == 0) {  // wave-uniform; isolated/invalid -> max_agg = 0
                m0 = make_float2(0.f, 0.f); m1 = m0; m2 = m0;
            }
            mx[n][0] = m0; mx[n][1] = m1; mx[n][2] = m2;
            s16[n] = s; dgv[n] = dg;
        }
        // projection: one sweep over W serves 4 nodes; reduce-scatter per k-group
        float outv = 0.f;
#pragma unroll
        for (int kg = 0; kg < 4; kg++) {
            float r[16];
#pragma unroll
            for (int kk = 0; kk < 4; kk++) {
                int k = (kg << 2) + kk;
                float2 w0 = *(const float2*)(wp + k * IN_DIM);
                float2 w1 = *(const float2*)(wp + k * IN_DIM + 128);
                float2 w2 = *(const float2*)(wp + k * IN_DIM + 256);
#pragma unroll
                for (int n = 0; n < 4; n++) {
                    float t = mx[n][0].x * w0.x;
                    t = fmaf(mx[n][0].y, w0.y, t);
                    t = fmaf(mx[n][1].x, w1.x, t);
                    t = fmaf(mx[n][1].y, w1.y, t);
                    t = fmaf(mx[n][2].x, w2.x, t);
                    t = fmaf(mx[n][2].y, w2.y, t);
                    r[(n << 2) + kk] = t;
                }
            }
#pragma unroll
            for (int s = 0; s < 4; s++) {
                int step = 1 << s;
                bool hi = (lane & step) != 0;
#pragma unroll
                for (int m = 0; m < (8 >> s); m++) {
                    float a = r[2 * m], b = r[2 * m + 1];
                    float send = hi ? a : b;
                    float keep = hi ? b : a;
                    r[m] = keep + __shfl_xor(send, step, 64);
                }
            }
            float v = r[0];
            v += __shfl_xor(v, 16, 64);
            v += __shfl_xor(v, 32, 64);
            if ((lane >> 4) == kg) outv = v;
        }
        // epilogue: lane l owns (node nq, channel kq); h-write is contiguous
        int iw = ibase + nq;
        float t0 = __shfl(s16[0], kq, 64), t1 = __shfl(s16[1], kq, 64);
        float t2 = __shfl(s16[2], kq, 64), t3 = __shfl(s16[3], kq, 64);
        float sv = (nq == 0) ? t0 : (nq == 1) ? t1 : (nq == 2) ? t2 : t3;
        int dgs = (nq == 0) ? dgv[0] : (nq == 1) ? dgv[1] : (nq == 2) ? dgv[2] : dgv[3];
        if (iw < N) {
            float mean = sv / (float)max(dgs, 1);
            float hv = mean + outv + y[(size_t)iw * 32 + 16 + kq] + lbv;
            h[(size_t)iw * HID + kq] = hv;
            sAcc += hv;
            s2Acc = fmaf(hv, hv, s2Acc);
        }
    }
    __syncthreads();
    atomicAdd(&shS[kq], sAcc);
    atomicAdd(&shS[16 + kq], s2Acc);
    __syncthreads();
    if (threadIdx.x < 32) atomicAdd(&stats[threadIdx.x], shS[threadIdx.x]);
}

// ---------------- BN + ReLU + global mean pool (LDS pre-aggregation; batch sorted)
__global__ __launch_bounds__(256) void k_pool(const float* __restrict__ h,
                                              const int* __restrict__ batch,
                                              const float* __restrict__ stats,
                                              const float* __restrict__ gamma,
                                              const float* __restrict__ beta, int N,
                                              float* __restrict__ pooled,
                                              int* __restrict__ gcnt) {
    __shared__ float smP[MAXG * HID];
    __shared__ int smC[MAXG];
    for (int idx = threadIdx.x; idx < MAXG * HID; idx += blockDim.x) smP[idx] = 0.f;
    if (threadIdx.x < MAXG) smC[threadIdx.x] = 0;
    __syncthreads();
    int c = threadIdx.x & 15;
    float invN = 1.f / (float)N;
    float mu = stats[c] * invN;
    float var = stats[16 + c] * invN - mu * mu;
    float sc = gamma[c] * rsqrtf(var + BN_EPS);
    float sh = beta[c] - mu * sc;
    int base = blockIdx.x * 1024;
    int endn = min(base + 1024, N);
    for (int idx = base * HID + threadIdx.x; idx < endn * HID; idx += blockDim.x) {
        int n = idx >> 4;
        float v = fmaxf(fmaf(h[idx], sc, sh), 0.f);
        int g = batch[n] & (MAXG - 1);
        atomicAdd(&smP[g * HID + c], v);
        if (c == 0) atomicAdd(&smC[g], 1);
    }
    __syncthreads();
    for (int idx = threadIdx.x; idx < MAXG * HID; idx += blockDim.x)
        if (smP[idx] != 0.f) atomicAdd(&pooled[idx], smP[idx]);
    if (threadIdx.x < MAXG && smC[threadIdx.x]) atomicAdd(&gcnt[threadIdx.x], smC[threadIdx.x]);
}

// ---------------- pooled mean + FC
__global__ void k_final(const float* __restrict__ pooled, const int* __restrict__ gcnt,
                        const float* __restrict__ fcw, const float* __restrict__ fcb, int G,
                        float* __restrict__ out) {
    int g = threadIdx.x;
    if (g < G) {
        float inv = 1.f / (float)max(gcnt[g], 1);
        float o0 = fcb[0], o1 = fcb[1];
#pragma unroll
        for (int ch = 0; ch < HID; ch++) {
            float pv = pooled[g * HID + ch] * inv;
            o0 = fmaf(pv, fcw[ch], o0);
            o1 = fmaf(pv, fcw[HID + ch], o1);
        }
        out[g * NCLS + 0] = o0;
        out[g * NCLS + 1] = o1;
    }
}

extern "C" void kernel_launch(void* const* d_in, const int* in_sizes, int n_in,
                              void* d_out, int out_size, void* d_ws, size_t ws_size,
                              hipStream_t stream) {
    const float* x = (const float*)d_in[0];
    const int* ei = (const int*)d_in[1];
    const int* batch = (const int*)d_in[2];
    const float* wl = (const float*)d_in[4];
    const float* lb = (const float*)d_in[5];
    const float* wr = (const float*)d_in[6];
    const float* gamma = (const float*)d_in[7];
    const float* beta = (const float*)d_in[8];
    const float* fcw = (const float*)d_in[9];
    const float* fcb = (const float*)d_in[10];

    const int N = in_sizes[0] / IN_DIM;
    const int E = in_sizes[1] / 2;
    const int G = out_size / NCLS;
    const int* ej = ei + E;

    size_t off = 0;
    auto take = [&](size_t b) { size_t r = off; off += (b + 255) & ~(size_t)255; return r; };
    size_t deg_off  = take((size_t)N * 4);
    size_t cur_off  = take(4);
    size_t stat_off = take(32 * 4);
    size_t pool_off = take((size_t)MAXG * HID * 4);
    size_t gcnt_off = take((size_t)MAXG * 4);
    size_t zero_bytes = off;
    size_t dof_off  = take((size_t)N * 8);
    size_t wcur_off = take((size_t)N * 4);
    size_t col_off  = take((size_t)E * 4);
    size_t y_off    = take((size_t)N * 32 * 4);
    size_t h_off    = take((size_t)N * HID * 4);
    (void)ws_size;

    char* ws = (char*)d_ws;
    int* deg = (int*)(ws + deg_off);
    int* cursor = (int*)(ws + cur_off);
    float* stats = (float*)(ws + stat_off);
    float* pooled = (float*)(ws + pool_off);
    int* gcnt = (int*)(ws + gcnt_off);
    int2* degoffs = (int2*)(ws + dof_off);
    int* wcur = (int*)(ws + wcur_off);
    int* colidx = (int*)(ws + col_off);
    float* y = (float*)(ws + y_off);
    float* h = (float*)(ws + h_off);

    hipMemsetAsync(d_ws, 0, zero_bytes, stream);

    int eblocks = (E + 255) / 256;
    int ngroups = (N + 3) >> 2;
    k_hist<<<eblocks, 256, 0, stream>>>(ei, E, deg);
    k_alloc<<<(N + 255) / 256, 256, 0, stream>>>(deg, N, degoffs, wcur, cursor);
    k_scatter<<<eblocks, 256, 0, stream>>>(ei, ej, E, wcur, colidx);
    k_proj<<<(N + 63) / 64, 512, 0, stream>>>(x, wl, wr, N, y);
    k_node<<<(ngroups + 3) / 4, 256, 0, stream>>>(x, y, wl, lb, degoffs, colidx, N, h, stats);
    k_pool<<<(N + 1023) / 1024, 256, 0, stream>>>(h, batch, stats, gamma, beta, N, pooled, gcnt);
    k_final<<<1, 64, 0, stream>>>(pooled, gcnt, fcw, fcb, G, (float*)d_out);
}

// Round 5
// 186.688 us; speedup vs baseline: 1.1843x; 1.0928x over previous
//
#include <hip/hip_runtime.h>
#include <math.h>

#define IN_DIM 384
#define HID 16
#define NCLS 2
#define BN_EPS 1e-5f
#define MAXG 64

__device__ __forceinline__ unsigned bf16r(float f) {  // RNE fp32->bf16 (monotone)
    unsigned u = __float_as_uint(f);
    return (u + 0x7fffu + ((u >> 16) & 1u)) >> 16;
}
#define LOF(u) __uint_as_float((u) << 16)
#define HIF(u) __uint_as_float((u) & 0xffff0000u)

// ---------------- CSR build ----------------
__global__ void k_hist(const int* __restrict__ ei, int E, int* __restrict__ deg) {
    int stride = gridDim.x * blockDim.x;
    for (int e = blockIdx.x * blockDim.x + threadIdx.x; e < E; e += stride)
        atomicAdd(&deg[ei[e]], 1);
}

__global__ void k_alloc(const int* __restrict__ deg, int N, int2* __restrict__ degoffs,
                        int* __restrict__ wcur, int* __restrict__ cursor) {
    int i = blockIdx.x * blockDim.x + threadIdx.x;
    int lane = threadIdx.x & 63;
    int d = (i < N) ? deg[i] : 0;
    int run = d;
#pragma unroll
    for (int s = 1; s < 64; s <<= 1) {
        int v = __shfl_up(run, s, 64);
        if (lane >= s) run += v;
    }
    int total = __shfl(run, 63, 64);
    int base = 0;
    if (lane == 63) base = atomicAdd(cursor, total);
    base = __shfl(base, 63, 64);
    if (i < N) {
        int o = base + run - d;
        degoffs[i] = make_int2(o, d);
        wcur[i] = o;
    }
}

__global__ void k_scatter(const int* __restrict__ ei, const int* __restrict__ ej, int E,
                          int* __restrict__ wcur, int* __restrict__ colidx) {
    int stride = gridDim.x * blockDim.x;
    for (int e = blockIdx.x * blockDim.x + threadIdx.x; e < E; e += stride) {
        int i = ei[e];
        int pos = atomicAdd(&wcur[i], 1);
        colidx[pos] = ej[e];
    }
}

// ---------------- pre-projection (wave per 4 nodes, reduce-scatter):
// y[i][0..15] = x@W_mean.T, y[i][16..31] = x@W_root.T; also emits bf16 copy xb.
__global__ __launch_bounds__(256) void k_proj(const float* __restrict__ x,
                                              const float* __restrict__ wl,
                                              const float* __restrict__ wr, int N,
                                              float* __restrict__ y,
                                              unsigned* __restrict__ xb) {
    int lane = threadIdx.x & 63;
    int wid = threadIdx.x >> 6;
    int kq = ((lane >> 4) << 2) + (lane & 3);
    int nq = (lane & 15) >> 2;
    int ngroups = (N + 3) >> 2;
    int g = blockIdx.x * 4 + wid;
    if (g >= ngroups) return;
    int ibase = g << 2;
    float2 xv[4][3];
#pragma unroll
    for (int n = 0; n < 4; n++) {
        int i = min(ibase + n, N - 1);
        const float* xr = x + (size_t)i * IN_DIM + 2 * lane;
        xv[n][0] = *(const float2*)xr;
        xv[n][1] = *(const float2*)(xr + 128);
        xv[n][2] = *(const float2*)(xr + 256);
    }
#pragma unroll
    for (int n = 0; n < 4; n++) {
        int i = ibase + n;
        if (i < N) {
            unsigned* xo = xb + (size_t)i * 192 + lane;
#pragma unroll
            for (int c = 0; c < 3; c++) {
                unsigned lo = bf16r(xv[n][c].x);
                unsigned hi = bf16r(xv[n][c].y);
                xo[c * 64] = lo | (hi << 16);
            }
        }
    }
    float out0 = 0.f, out1 = 0.f;
#pragma unroll
    for (int kg = 0; kg < 8; kg++) {
        float r[16];
#pragma unroll
        for (int kk = 0; kk < 4; kk++) {
            int k = ((kg & 3) << 2) + kk;
            const float* wrow = (kg < 4) ? (wl + (size_t)k * (2 * IN_DIM) + 2 * lane)
                                         : (wr + (size_t)k * IN_DIM + 2 * lane);
            float2 w0 = *(const float2*)wrow;
            float2 w1 = *(const float2*)(wrow + 128);
            float2 w2 = *(const float2*)(wrow + 256);
#pragma unroll
            for (int n = 0; n < 4; n++) {
                float t = xv[n][0].x * w0.x;
                t = fmaf(xv[n][0].y, w0.y, t);
                t = fmaf(xv[n][1].x, w1.x, t);
                t = fmaf(xv[n][1].y, w1.y, t);
                t = fmaf(xv[n][2].x, w2.x, t);
                t = fmaf(xv[n][2].y, w2.y, t);
                r[(n << 2) + kk] = t;
            }
        }
#pragma unroll
        for (int st = 0; st < 4; st++) {
            int step = 1 << st;
            bool hi = (lane & step) != 0;
#pragma unroll
            for (int m = 0; m < (8 >> st); m++) {
                float a = r[2 * m], b = r[2 * m + 1];
                float send = hi ? a : b;
                float keep = hi ? b : a;
                r[m] = keep + __shfl_xor(send, step, 64);
            }
        }
        float v = r[0];
        v += __shfl_xor(v, 16, 64);
        v += __shfl_xor(v, 32, 64);
        if ((lane >> 4) == (kg & 3)) {
            if (kg < 4) out0 = v;
            else out1 = v;
        }
    }
    int iw = ibase + nq;
    if (iw < N) {
        y[(size_t)iw * 32 + kq] = out0;
        y[(size_t)iw * 32 + 16 + kq] = out1;
    }
}

// ---------------- wave-per-4-nodes: bf16 gather-max (padded 4-edge chunks,
// duplicate edges are idempotent for max, masked for mean-sum), projection
// through global W_max, reduce-scatter, fused BN-stats. LDS ~= 128 B.
__global__ __launch_bounds__(256) void k_node(const unsigned* __restrict__ xb,
                                              const float* __restrict__ y,
                                              const float* __restrict__ wl,
                                              const float* __restrict__ lb,
                                              const int2* __restrict__ degoffs,
                                              const int* __restrict__ colidx, int N,
                                              float* __restrict__ h,
                                              float* __restrict__ stats) {
    __shared__ float shS[32];
    if (threadIdx.x < 32) shS[threadIdx.x] = 0.f;
    __syncthreads();
    int lane = threadIdx.x & 63;
    int wid = threadIdx.x >> 6;
    int kq = ((lane >> 4) << 2) + (lane & 3);  // channel this lane finalizes
    int nq = (lane & 15) >> 2;                 // node slot this lane finalizes
    int slot = lane >> 4;                      // edge slot for y-gather
    int ch = lane & 15;                        // y channel for y-gather
    float sAcc = 0.f, s2Acc = 0.f;
    int ngroups = (N + 3) >> 2;
    int g = blockIdx.x * 4 + wid;
    if (g < ngroups) {
        int ibase = g << 2;
        int2 dof[4];
        int jpre[4];
#pragma unroll
        for (int n = 0; n < 4; n++)
            dof[n] = (ibase + n < N) ? degoffs[ibase + n] : make_int2(0, 0);
#pragma unroll
        for (int n = 0; n < 4; n++)
            jpre[n] = (dof[n].y > 0) ? colidx[dof[n].x + min(lane, dof[n].y - 1)] : 0;
        float2 mx[4][3];
        float sd[4];
        int dgv[4];
#pragma unroll
        for (int n = 0; n < 4; n++) {
            int beg = dof[n].x, dg = dof[n].y;
            dgv[n] = dg;
            float2 m0 = make_float2(-INFINITY, -INFINITY), m1 = m0, m2 = m0;
            float s = 0.f;
            for (int e0 = 0; e0 < dg; e0 += 64) {
                int nv = min(64, dg - e0);
                int jv = (e0 == 0) ? jpre[n] : colidx[beg + min(e0 + lane, dg - 1)];
                for (int eb = 0; eb < nv; eb += 4) {
                    int j0 = __shfl(jv, eb, 64);
                    int j1 = __shfl(jv, eb + 1, 64);
                    int j2 = __shfl(jv, eb + 2, 64);
                    int j3 = __shfl(jv, eb + 3, 64);
                    const unsigned* q0 = xb + (size_t)j0 * 192 + lane;
                    const unsigned* q1 = xb + (size_t)j1 * 192 + lane;
                    const unsigned* q2 = xb + (size_t)j2 * 192 + lane;
                    const unsigned* q3 = xb + (size_t)j3 * 192 + lane;
                    unsigned a0 = q0[0], a1 = q0[64], a2 = q0[128];
                    unsigned b0 = q1[0], b1 = q1[64], b2 = q1[128];
                    unsigned c0 = q2[0], c1 = q2[64], c2 = q2[128];
                    unsigned d0 = q3[0], d1 = q3[64], d2 = q3[128];
                    int js = (slot == 0) ? j0 : (slot == 1) ? j1 : (slot == 2) ? j2 : j3;
                    float yv = y[(size_t)js * 32 + ch];
                    s += (eb + slot < nv) ? yv : 0.f;
                    m0.x = fmaxf(fmaxf(m0.x, fmaxf(LOF(a0), LOF(b0))), fmaxf(LOF(c0), LOF(d0)));
                    m0.y = fmaxf(fmaxf(m0.y, fmaxf(HIF(a0), HIF(b0))), fmaxf(HIF(c0), HIF(d0)));
                    m1.x = fmaxf(fmaxf(m1.x, fmaxf(LOF(a1), LOF(b1))), fmaxf(LOF(c1), LOF(d1)));
                    m1.y = fmaxf(fmaxf(m1.y, fmaxf(HIF(a1), HIF(b1))), fmaxf(HIF(c1), HIF(d1)));
                    m2.x = fmaxf(fmaxf(m2.x, fmaxf(LOF(a2), LOF(b2))), fmaxf(LOF(c2), LOF(d2)));
                    m2.y = fmaxf(fmaxf(m2.y, fmaxf(HIF(a2), HIF(b2))), fmaxf(HIF(c2), HIF(d2)));
                }
            }
            if (dg == 0) {  // wave-uniform; isolated/invalid -> max_agg = 0
                m0 = make_float2(0.f, 0.f); m1 = m0; m2 = m0;
            }
            mx[n][0] = m0; mx[n][1] = m1; mx[n][2] = m2;
            sd[n] = s;
        }
#pragma unroll
        for (int n = 0; n < 4; n++) {
            sd[n] += __shfl_xor(sd[n], 16, 64);
            sd[n] += __shfl_xor(sd[n], 32, 64);
        }
        // projection: W_max from global (L2-hot 24 KB); one sweep serves 4 nodes
        const float* wp = wl + IN_DIM + 2 * lane;  // max part of lin_l rows
        float outv = 0.f;
#pragma unroll
        for (int kg = 0; kg < 4; kg++) {
            float r[16];
#pragma unroll
            for (int kk = 0; kk < 4; kk++) {
                int k = (kg << 2) + kk;
                const float* wrow = wp + (size_t)k * (2 * IN_DIM);
                float2 w0 = *(const float2*)wrow;
                float2 w1 = *(const float2*)(wrow + 128);
                float2 w2 = *(const float2*)(wrow + 256);
#pragma unroll
                for (int n = 0; n < 4; n++) {
                    float t = mx[n][0].x * w0.x;
                    t = fmaf(mx[n][0].y, w0.y, t);
                    t = fmaf(mx[n][1].x, w1.x, t);
                    t = fmaf(mx[n][1].y, w1.y, t);
                    t = fmaf(mx[n][2].x, w2.x, t);
                    t = fmaf(mx[n][2].y, w2.y, t);
                    r[(n << 2) + kk] = t;
                }
            }
#pragma unroll
            for (int st = 0; st < 4; st++) {
                int step = 1 << st;
                bool hi = (lane & step) != 0;
#pragma unroll
                for (int m = 0; m < (8 >> st); m++) {
                    float a = r[2 * m], b = r[2 * m + 1];
                    float send = hi ? a : b;
                    float keep = hi ? b : a;
                    r[m] = keep + __shfl_xor(send, step, 64);
                }
            }
            float v = r[0];
            v += __shfl_xor(v, 16, 64);
            v += __shfl_xor(v, 32, 64);
            if ((lane >> 4) == kg) outv = v;
        }
        // epilogue: lane owns (node nq, channel kq); contiguous h-write
        int iw = ibase + nq;
        float t0 = __shfl(sd[0], kq, 64), t1 = __shfl(sd[1], kq, 64);
        float t2 = __shfl(sd[2], kq, 64), t3 = __shfl(sd[3], kq, 64);
        float sv = (nq == 0) ? t0 : (nq == 1) ? t1 : (nq == 2) ? t2 : t3;
        int dgs = (nq == 0) ? dgv[0] : (nq == 1) ? dgv[1] : (nq == 2) ? dgv[2] : dgv[3];
        if (iw < N) {
            float mean = sv / (float)max(dgs, 1);
            float hv = mean + outv + y[(size_t)iw * 32 + 16 + kq] + lb[kq];
            h[(size_t)iw * HID + kq] = hv;
            sAcc += hv;
            s2Acc = fmaf(hv, hv, s2Acc);
        }
    }
    __syncthreads();
    atomicAdd(&shS[kq], sAcc);
    atomicAdd(&shS[16 + kq], s2Acc);
    __syncthreads();
    if (threadIdx.x < 32) atomicAdd(&stats[threadIdx.x], shS[threadIdx.x]);
}

// ---------------- BN + ReLU + global mean pool (LDS pre-aggregation; batch sorted)
__global__ __launch_bounds__(256) void k_pool(const float* __restrict__ h,
                                              const int* __restrict__ batch,
                                              const float* __restrict__ stats,
                                              const float* __restrict__ gamma,
                                              const float* __restrict__ beta, int N,
                                              float* __restrict__ pooled,
                                              int* __restrict__ gcnt) {
    __shared__ float smP[MAXG * HID];
    __shared__ int smC[MAXG];
    for (int idx = threadIdx.x; idx < MAXG * HID; idx += blockDim.x) smP[idx] = 0.f;
    if (threadIdx.x < MAXG) smC[threadIdx.x] = 0;
    __syncthreads();
    int c = threadIdx.x & 15;
    float invN = 1.f / (float)N;
    float mu = stats[c] * invN;
    float var = stats[16 + c] * invN - mu * mu;
    float sc = gamma[c] * rsqrtf(var + BN_EPS);
    float sh = beta[c] - mu * sc;
    int base = blockIdx.x * 1024;
    int endn = min(base + 1024, N);
    for (int idx = base * HID + threadIdx.x; idx < endn * HID; idx += blockDim.x) {
        int n = idx >> 4;
        float v = fmaxf(fmaf(h[idx], sc, sh), 0.f);
        int g = batch[n] & (MAXG - 1);
        atomicAdd(&smP[g * HID + c], v);
        if (c == 0) atomicAdd(&smC[g], 1);
    }
    __syncthreads();
    for (int idx = threadIdx.x; idx < MAXG * HID; idx += blockDim.x)
        if (smP[idx] != 0.f) atomicAdd(&pooled[idx], smP[idx]);
    if (threadIdx.x < MAXG && smC[threadIdx.x]) atomicAdd(&gcnt[threadIdx.x], smC[threadIdx.x]);
}

// ---------------- pooled mean + FC
__global__ void k_final(const float* __restrict__ pooled, const int* __restrict__ gcnt,
                        const float* __restrict__ fcw, const float* __restrict__ fcb, int G,
                        float* __restrict__ out) {
    int g = threadIdx.x;
    if (g < G) {
        float inv = 1.f / (float)max(gcnt[g], 1);
        float o0 = fcb[0], o1 = fcb[1];
#pragma unroll
        for (int ch = 0; ch < HID; ch++) {
            float pv = pooled[g * HID + ch] * inv;
            o0 = fmaf(pv, fcw[ch], o0);
            o1 = fmaf(pv, fcw[HID + ch], o1);
        }
        out[g * NCLS + 0] = o0;
        out[g * NCLS + 1] = o1;
    }
}

extern "C" void kernel_launch(void* const* d_in, const int* in_sizes, int n_in,
                              void* d_out, int out_size, void* d_ws, size_t ws_size,
                              hipStream_t stream) {
    const float* x = (const float*)d_in[0];
    const int* ei = (const int*)d_in[1];
    const int* batch = (const int*)d_in[2];
    const float* wl = (const float*)d_in[4];
    const float* lb = (const float*)d_in[5];
    const float* wr = (const float*)d_in[6];
    const float* gamma = (const float*)d_in[7];
    const float* beta = (const float*)d_in[8];
    const float* fcw = (const float*)d_in[9];
    const float* fcb = (const float*)d_in[10];

    const int N = in_sizes[0] / IN_DIM;
    const int E = in_sizes[1] / 2;
    const int G = out_size / NCLS;
    const int* ej = ei + E;

    size_t off = 0;
    auto take = [&](size_t b) { size_t r = off; off += (b + 255) & ~(size_t)255; return r; };
    size_t deg_off  = take((size_t)N * 4);
    size_t cur_off  = take(4);
    size_t stat_off = take(32 * 4);
    size_t pool_off = take((size_t)MAXG * HID * 4);
    size_t gcnt_off = take((size_t)MAXG * 4);
    size_t zero_bytes = off;
    size_t dof_off  = take((size_t)N * 8);
    size_t wcur_off = take((size_t)N * 4);
    size_t col_off  = take((size_t)E * 4);
    size_t y_off    = take((size_t)N * 32 * 4);
    size_t h_off    = take((size_t)N * HID * 4);
    size_t xb_off   = take((size_t)N * 192 * 4);
    (void)ws_size;

    char* ws = (char*)d_ws;
    int* deg = (int*)(ws + deg_off);
    int* cursor = (int*)(ws + cur_off);
    float* stats = (float*)(ws + stat_off);
    float* pooled = (float*)(ws + pool_off);
    int* gcnt = (int*)(ws + gcnt_off);
    int2* degoffs = (int2*)(ws + dof_off);
    int* wcur = (int*)(ws + wcur_off);
    int* colidx = (int*)(ws + col_off);
    float* y = (float*)(ws + y_off);
    float* h = (float*)(ws + h_off);
    unsigned* xb = (unsigned*)(ws + xb_off);

    hipMemsetAsync(d_ws, 0, zero_bytes, stream);

    int eblocks = (E + 255) / 256;
    int ngroups = (N + 3) >> 2;
    int gblocks = (ngroups + 3) / 4;
    k_hist<<<eblocks, 256, 0, stream>>>(ei, E, deg);
    k_alloc<<<(N + 255) / 256, 256, 0, stream>>>(deg, N, degoffs, wcur, cursor);
    k_scatter<<<eblocks, 256, 0, stream>>>(ei, ej, E, wcur, colidx);
    k_proj<<<gblocks, 256, 0, stream>>>(x, wl, wr, N, y, xb);
    k_node<<<gblocks, 256, 0, stream>>>(xb, y, wl, lb, degoffs, colidx, N, h, stats);
    k_pool<<<(N + 1023) / 1024, 256, 0, stream>>>(h, batch, stats, gamma, beta, N, pooled, gcnt);
    k_final<<<1, 64, 0, stream>>>(pooled, gcnt, fcw, fcb, G, (float*)d_out);
}